// Round 4
// baseline (882.044 us; speedup 1.0000x reference)
//
#include <hip/hip_runtime.h>

// WaveRNN: 2D wave equation, T=512 sequential steps, B=4 batches of 160x160.
// One workgroup per batch; 32x32 threads each owning a 5x5 register patch.
// Column halos via DPP wave shifts; row halos via 16B-aligned LDS edge rows
// (ds_read_b128 + ds_read_b32). Double-buffered edges -> 1 barrier per step.
// Time loop unrolled x2 with A/B register-array swap (no h2<-h1 copies).
// [Resubmit of round-3 kernel: previous bench died to an infra error.]

#define NB 4
#define NT 512
#define NN 160
#define NP 32
#define C_DT 0.16f

#define TGY 32
#define TGX 32
#define PR 5
#define PC 5
#define K_ENT 6
#define EROWS (2*TGY + 2)   // 66: rows 0 and 65 are permanent zero guards

typedef float f4 __attribute__((ext_vector_type(4)));

#if defined(__has_builtin)
#if __has_builtin(__builtin_amdgcn_update_dpp)
#define HAVE_DPP 1
#endif
#endif

__device__ __forceinline__ float shr1(float v) {   // lane i <- lane i-1
#ifdef HAVE_DPP
    return __int_as_float(__builtin_amdgcn_update_dpp(
        0, __float_as_int(v), 0x138 /*wave_shr:1*/, 0xf, 0xf, true));
#else
    return __shfl_up(v, 1, 64);
#endif
}
__device__ __forceinline__ float shl1(float v) {   // lane i <- lane i+1
#ifdef HAVE_DPP
    return __int_as_float(__builtin_amdgcn_update_dpp(
        0, __float_as_int(v), 0x130 /*wave_shl:1*/, 0xf, 0xf, true));
#else
    return __shfl_down(v, 1, 64);
#endif
}

__global__ __launch_bounds__(1024, 1) void wave_kernel(
    const float* __restrict__ x,      // [B][T]
    const float* __restrict__ cmat,   // [N][N]
    const float* __restrict__ rho,    // [N][N]
    const int*   __restrict__ src_i_p,
    const int*   __restrict__ src_j_p,
    const int*   __restrict__ probe_i,// [P]
    const int*   __restrict__ probe_j,// [P]
    float*       __restrict__ y)      // [B][T][P]
{
    // [parity][edge-row][tx][8]: slots 0..4 hold the 5-float row segment,
    // 32B stride per tx => 16B-aligned b128+b32 access, banks evenly covered.
    __shared__ float eb[2][EROWS][TGX][8];
    __shared__ float pb[2][NP];
    __shared__ float xbuf[NT];
    __shared__ int   pco[2*NP];

    const int b   = blockIdx.x;
    const int tid = threadIdx.x;
    const int ty  = tid >> 5;
    const int tx  = tid & 31;
    const int r0  = ty * PR;
    const int c0  = tx * PC;

    // ---- init: zero both edge buffers (initial field is 0), stage x ----
    {
        float* ez = &eb[0][0][0][0];
        for (int i = tid; i < 2*EROWS*TGX*8; i += TGY*TGX) ez[i] = 0.0f;
        for (int i = tid; i < NT; i += TGY*TGX) xbuf[i] = x[b*NT + i];
        if (tid < NP) { pco[tid] = probe_i[tid]; pco[NP + tid] = probe_j[tid]; }
        if (tid < 2*NP) pb[0][tid] = 0.0f;   // pb is [2][NP] contiguous
    }

    const int si = src_i_p[0];
    const int sj = src_j_p[0];

    float hA[PR][PC], hB[PR][PC], cf[PR][PC], c2[PR][PC];
    #pragma unroll
    for (int i = 0; i < PR; ++i)
        #pragma unroll
        for (int j = 0; j < PC; ++j) {
            const int r = r0 + i, c = c0 + j;
            const float cc = cmat[r*NN + c];
            const float rr = rho[r*NN + c];
            cf[i][j] = C_DT * cc * cc / rr;
            c2[i][j] = 2.0f - 4.0f * cf[i][j];
            hA[i][j] = 0.0f;
            hB[i][j] = 0.0f;
        }

    unsigned srcMask = 0;
    if (r0 <= si && si < r0 + PR && c0 <= sj && sj < c0 + PC)
        srcMask = 1u << ((si - r0)*PC + (sj - c0));

    __syncthreads();

    // packed probe ownership: up to K_ENT entries of (p:5 | cell:5) << 10k
    unsigned long long ent = 0;
    int ecnt = 0;
    for (int p = 0; p < NP; ++p) {
        const int r = pco[p], c = pco[NP + p];
        if (r >= r0 && r < r0 + PR && c >= c0 && c < c0 + PC) {
            const int ij = (r - r0)*PC + (c - c0);
            if (ecnt < K_ENT)
                ent |= ((unsigned long long)(unsigned)(p | (ij << 5))) << (10*ecnt);
            ecnt++;
        }
    }

    float* const yb = y + (size_t)b*NT*NP;

// One time step. HS = current h1, HD = h2 in / h1 out.
// PIN = parity of edge buffer read (state of step tt), POUT = write parity.
#define STEP(HS, HD, TT, PIN, POUT)                                           \
    {                                                                         \
        const int tt = (TT);                                                  \
        /* issue halo reads first (b128+b32 each row) */                      \
        const f4    nh4 = *(const f4*)&eb[PIN][2*ty    ][tx][0];              \
        const float nhe = eb[PIN][2*ty    ][tx][4];                           \
        const f4    sh4 = *(const f4*)&eb[PIN][2*ty + 3][tx][0];              \
        const float she = eb[PIN][2*ty + 3][tx][4];                           \
        /* flush previous step's probes */                                    \
        if (tt > 0 && tid < NP) yb[(size_t)(tt-1)*NP + tid] = pb[PIN][tid];   \
        const float nh[PC] = { nh4[0], nh4[1], nh4[2], nh4[3], nhe };         \
        const float sh[PC] = { sh4[0], sh4[1], sh4[2], sh4[3], she };         \
        float wh[PR], eh[PR];                                                 \
        _Pragma("unroll")                                                     \
        for (int i = 0; i < PR; ++i) {                                        \
            const float tw = shr1(HS[i][PC-1]);                               \
            wh[i] = (tx == 0) ? 0.0f : tw;                                    \
            const float te = shl1(HS[i][0]);                                  \
            eh[i] = (tx == TGX-1) ? 0.0f : te;                                \
        }                                                                     \
        _Pragma("unroll")                                                     \
        for (int i = 0; i < PR; ++i) {                                        \
            _Pragma("unroll")                                                 \
            for (int j = 0; j < PC; ++j) {                                    \
                const float up = (i == 0)    ? nh[j] : HS[i-1][j];            \
                const float dn = (i == PR-1) ? sh[j] : HS[i+1][j];            \
                const float lf = (j == 0)    ? wh[i] : HS[i][j-1];            \
                const float rt = (j == PC-1) ? eh[i] : HS[i][j+1];            \
                const float s  = (up + dn) + (lf + rt);                       \
                /* hn = cf*s + ((2-4cf)*h1 - h2) */                           \
                const float t1 = __builtin_fmaf(c2[i][j], HS[i][j], -HD[i][j]); \
                HD[i][j] = __builtin_fmaf(cf[i][j], s, t1);                   \
            }                                                                 \
        }                                                                     \
        if (srcMask) {                                                        \
            const float xt = xbuf[tt];                                        \
            _Pragma("unroll")                                                 \
            for (int i = 0; i < PR; ++i)                                      \
                _Pragma("unroll")                                             \
                for (int j = 0; j < PC; ++j)                                  \
                    if (srcMask & (1u << (i*PC + j))) HD[i][j] += xt;         \
        }                                                                     \
        /* publish new edges (b128+b32 each) + probes to the POUT buffers */  \
        *(f4*)&eb[POUT][2*ty + 1][tx][0] =                                    \
            (f4){ HD[0][0], HD[0][1], HD[0][2], HD[0][3] };                   \
        eb[POUT][2*ty + 1][tx][4] = HD[0][4];                                 \
        *(f4*)&eb[POUT][2*ty + 2][tx][0] =                                    \
            (f4){ HD[PR-1][0], HD[PR-1][1], HD[PR-1][2], HD[PR-1][3] };       \
        eb[POUT][2*ty + 2][tx][4] = HD[PR-1][4];                              \
        if (ecnt) {                                                           \
            _Pragma("unroll")                                                 \
            for (int k = 0; k < K_ENT; ++k) {                                 \
                if (k < ecnt) {                                               \
                    const int e  = (int)((ent >> (10*k)) & 0x3FF);            \
                    const int p  = e & 31;                                    \
                    const int ij = e >> 5;                                    \
                    float v = 0.0f;                                           \
                    _Pragma("unroll")                                         \
                    for (int i = 0; i < PR; ++i)                              \
                        _Pragma("unroll")                                     \
                        for (int j = 0; j < PC; ++j)                          \
                            if (ij == i*PC + j) v = HD[i][j];                 \
                    pb[POUT][p] = v;                                          \
                }                                                             \
            }                                                                 \
        }                                                                     \
        __syncthreads();  /* POUT buffers complete; PIN reads all drained */  \
    }

    for (int t = 0; t < NT; t += 2) {
        STEP(hA, hB, t,     0, 1);
        STEP(hB, hA, t + 1, 1, 0);
    }

    if (tid < NP) yb[(size_t)(NT-1)*NP + tid] = pb[0][tid];
#undef STEP
}

extern "C" void kernel_launch(void* const* d_in, const int* in_sizes, int n_in,
                              void* d_out, int out_size, void* d_ws, size_t ws_size,
                              hipStream_t stream) {
    const float* x    = (const float*)d_in[0];
    const float* cmat = (const float*)d_in[1];
    const float* rho  = (const float*)d_in[2];
    const int*   si   = (const int*)d_in[3];
    const int*   sj   = (const int*)d_in[4];
    const int*   pi   = (const int*)d_in[5];
    const int*   pj   = (const int*)d_in[6];
    float*       y    = (float*)d_out;

    wave_kernel<<<NB, TGY*TGX, 0, stream>>>(x, cmat, rho, si, sj, pi, pj, y);
}

// Round 5
// 740.710 us; speedup vs baseline: 1.1908x; 1.1908x over previous
//
#include <hip/hip_runtime.h>

// WaveRNN: 2D wave equation, T=512 steps, B=4 batches of 160x160.
// Ghost-zone decomposition: 4 blocks per batch (16 active blocks). Each block
// owns 40 rows, computes D=10 redundant halo rows per side; halo stays exact
// for 10 steps, then blocks exchange 10 boundary rows (h1+h2) via global
// memory with release/acquire flags (reset per launch by hipMemsetAsync).
// Intra-block: 5x5 register patches, DPP column halos, split f4+f1 LDS edge
// rows, double-buffered parity -> 1 barrier/step.

#define NB   4
#define NBK  4          // blocks per batch
#define OWN  40         // owned rows per block
#define D_EX 10         // halo depth == steps between exchanges
#define NT   512
#define NN   160
#define NP   32
#define C_DT 0.16f

#define TGX   32
#define TPR   12                 // max patch-rows (interior: (40+2*10)/5)
#define NTHR  (TPR*TGX)          // 384
#define EROWS (2*TPR + 2)        // 26; slots 0 and 25 are zero guards
#define K_ENT 6

#define SLAB      (D_EX*NN)              // floats per (side,level) slab: 1600
#define GB_FLOATS (NB*NBK*2*2*SLAB)      // 102400 floats = 409600 B
#define FLAG_OFF  (GB_FLOATS*4)          // byte offset of flags in d_ws

typedef float f4 __attribute__((ext_vector_type(4)));

#if defined(__has_builtin)
#if __has_builtin(__builtin_amdgcn_update_dpp)
#define HAVE_DPP 1
#endif
#endif

__device__ __forceinline__ float shr1(float v) {   // lane i <- lane i-1
#ifdef HAVE_DPP
    return __int_as_float(__builtin_amdgcn_update_dpp(
        0, __float_as_int(v), 0x138 /*wave_shr:1*/, 0xf, 0xf, true));
#else
    return __shfl_up(v, 1, 64);
#endif
}
__device__ __forceinline__ float shl1(float v) {   // lane i <- lane i+1
#ifdef HAVE_DPP
    return __int_as_float(__builtin_amdgcn_update_dpp(
        0, __float_as_int(v), 0x130 /*wave_shl:1*/, 0xf, 0xf, true));
#else
    return __shfl_down(v, 1, 64);
#endif
}

__global__ __launch_bounds__(NTHR, 1) void wave_kernel(
    const float* __restrict__ x,      // [B][T]
    const float* __restrict__ cmat,   // [N][N]
    const float* __restrict__ rho,    // [N][N]
    const int*   __restrict__ src_i_p,
    const int*   __restrict__ src_j_p,
    const int*   __restrict__ probe_i,// [P]
    const int*   __restrict__ probe_j,// [P]
    float*       __restrict__ y,      // [B][T][P]
    float*       __restrict__ gw,     // exchange slabs [B][NBK][side][lvl][10][160]
    int*         __restrict__ flags)  // [B*NBK], zeroed per launch
{
    __shared__ f4    eb4[2][EROWS][TGX];
    __shared__ float eb1[2][EROWS][TGX];
    __shared__ float xbuf[NT];
    __shared__ int   pco[2*NP];

    const int bid   = blockIdx.x;
    const int batch = bid & 7;        // same-batch blocks share an XCD (bid%8)
    if (batch >= NB) return;          // 16 idle pad blocks exit immediately
    const int blk   = bid >> 3;

    const int own_s = blk * OWN;
    const int own_e = own_s + OWN;
    const int ext_s = (own_s - D_EX < 0)  ? 0  : own_s - D_EX;
    const int ext_e = (own_e + D_EX > NN) ? NN : own_e + D_EX;
    const int npr   = (ext_e - ext_s) / 5;

    const int tid = threadIdx.x;
    const int pr  = tid >> 5;
    const int cg  = tid & 31;
    const bool act = pr < npr;
    const int gr0 = ext_s + 5*pr;     // global row of patch top (valid if act)
    const int c0  = 5*cg;

    // ---- init LDS ----
    {
        float* e4 = (float*)&eb4[0][0][0];
        for (int i = tid; i < 2*EROWS*TGX*4; i += NTHR) e4[i] = 0.0f;
        float* e1 = &eb1[0][0][0];
        for (int i = tid; i < 2*EROWS*TGX; i += NTHR) e1[i] = 0.0f;
        for (int i = tid; i < NT; i += NTHR) xbuf[i] = x[batch*NT + i];
        if (tid < NP) { pco[tid] = probe_i[tid]; pco[NP + tid] = probe_j[tid]; }
    }

    const int si = src_i_p[0];
    const int sj = src_j_p[0];

    float hA[5][5], hB[5][5], cf[5][5], c2[5][5];
    #pragma unroll
    for (int i = 0; i < 5; ++i)
        #pragma unroll
        for (int j = 0; j < 5; ++j) {
            float cfv = 0.0f;
            if (act) {
                const float cc = cmat[(gr0+i)*NN + (c0+j)];
                const float rr = rho[(gr0+i)*NN + (c0+j)];
                cfv = C_DT * cc * cc / rr;
            }
            cf[i][j] = cfv;
            c2[i][j] = 2.0f - 4.0f * cfv;
            hA[i][j] = 0.0f;
            hB[i][j] = 0.0f;
        }

    unsigned srcMask = 0;
    if (act && gr0 <= si && si < gr0 + 5 && c0 <= sj && sj < c0 + 5)
        srcMask = 1u << ((si - gr0)*5 + (sj - c0));

    __syncthreads();

    // probe ownership over OWNED cells only (exact every step)
    unsigned long long ent = 0;
    int ecnt = 0;
    if (act && gr0 >= own_s && gr0 < own_e) {
        for (int p = 0; p < NP; ++p) {
            const int r = pco[p], c = pco[NP + p];
            if (r >= gr0 && r < gr0 + 5 && c >= c0 && c < c0 + 5) {
                const int ij = (r - gr0)*5 + (c - c0);
                if (ecnt < K_ENT)
                    ent |= ((unsigned long long)(unsigned)(p | (ij << 5))) << (10*ecnt);
                ecnt++;
            }
        }
    }

    // ---- exchange pointers (per-thread constant) ----
    const int bid2 = batch*NBK + blk;
    float* sTop = nullptr; float* sBot = nullptr;
    const float* rTop = nullptr; const float* rBot = nullptr;
    if (blk > 0 && gr0 >= own_s && gr0 < own_s + D_EX)
        sTop = gw + (size_t)(bid2*2 + 0)*2*SLAB + (gr0 - own_s)*NN + c0;
    if (blk < NBK-1 && gr0 >= own_e - D_EX && gr0 < own_e)
        sBot = gw + (size_t)(bid2*2 + 1)*2*SLAB + (gr0 - (own_e - D_EX))*NN + c0;
    if (blk > 0 && act && gr0 < own_s)
        rTop = gw + (size_t)((bid2-1)*2 + 1)*2*SLAB + (gr0 - (own_s - D_EX))*NN + c0;
    if (blk < NBK-1 && act && gr0 >= own_e)
        rBot = gw + (size_t)((bid2+1)*2 + 0)*2*SLAB + (gr0 - own_e)*NN + c0;
    int* const flagSelf = &flags[bid2];
    int* const flagUp   = &flags[bid2 - 1];
    int* const flagDn   = &flags[bid2 + 1];

    float* const yb = y + (size_t)batch*NT*NP;

#define STEP(HS, HD, TT, PIN, POUT)                                           \
    {                                                                         \
        const int tt = (TT);                                                  \
        const f4    nh4 = eb4[PIN][2*pr    ][cg];                             \
        const float nhe = eb1[PIN][2*pr    ][cg];                             \
        const f4    sh4 = eb4[PIN][2*pr + 3][cg];                             \
        const float she = eb1[PIN][2*pr + 3][cg];                             \
        const float nh[5] = { nh4[0], nh4[1], nh4[2], nh4[3], nhe };          \
        const float sh[5] = { sh4[0], sh4[1], sh4[2], sh4[3], she };          \
        float wh[5], eh[5];                                                   \
        _Pragma("unroll")                                                     \
        for (int i = 0; i < 5; ++i) {                                         \
            const float tw = shr1(HS[i][4]);                                  \
            wh[i] = (cg == 0) ? 0.0f : tw;                                    \
            const float te = shl1(HS[i][0]);                                  \
            eh[i] = (cg == TGX-1) ? 0.0f : te;                                \
        }                                                                     \
        _Pragma("unroll")                                                     \
        for (int i = 0; i < 5; ++i) {                                         \
            _Pragma("unroll")                                                 \
            for (int j = 0; j < 5; ++j) {                                     \
                const float up = (i == 0) ? nh[j] : HS[i-1][j];               \
                const float dn = (i == 4) ? sh[j] : HS[i+1][j];               \
                const float lf = (j == 0) ? wh[i] : HS[i][j-1];               \
                const float rt = (j == 4) ? eh[i] : HS[i][j+1];               \
                const float s  = (up + dn) + (lf + rt);                       \
                const float t1 = __builtin_fmaf(c2[i][j], HS[i][j], -HD[i][j]); \
                HD[i][j] = __builtin_fmaf(cf[i][j], s, t1);                   \
            }                                                                 \
        }                                                                     \
        if (srcMask) {                                                        \
            const float xt = xbuf[tt];                                        \
            _Pragma("unroll")                                                 \
            for (int i = 0; i < 5; ++i)                                       \
                _Pragma("unroll")                                             \
                for (int j = 0; j < 5; ++j)                                   \
                    if (srcMask & (1u << (i*5 + j))) HD[i][j] += xt;          \
        }                                                                     \
        eb4[POUT][2*pr + 1][cg] = (f4){ HD[0][0], HD[0][1], HD[0][2], HD[0][3] }; \
        eb1[POUT][2*pr + 1][cg] = HD[0][4];                                   \
        eb4[POUT][2*pr + 2][cg] = (f4){ HD[4][0], HD[4][1], HD[4][2], HD[4][3] }; \
        eb1[POUT][2*pr + 2][cg] = HD[4][4];                                   \
        if (ecnt) {                                                           \
            float* const yt = yb + (size_t)tt * NP;                           \
            _Pragma("unroll")                                                 \
            for (int k = 0; k < K_ENT; ++k) {                                 \
                if (k < ecnt) {                                               \
                    const int e  = (int)((ent >> (10*k)) & 0x3FF);            \
                    const int p  = e & 31;                                    \
                    const int ij = e >> 5;                                    \
                    float v = 0.0f;                                           \
                    _Pragma("unroll")                                         \
                    for (int i = 0; i < 5; ++i)                               \
                        _Pragma("unroll")                                     \
                        for (int j = 0; j < 5; ++j)                           \
                            if (ij == i*5 + j) v = HD[i][j];                  \
                    yt[p] = v;                                                \
                }                                                             \
            }                                                                 \
        }                                                                     \
        __syncthreads();                                                      \
    }

    int t = 0, g = 0;
    while (t < NT) {
        const int steps = (NT - t < D_EX) ? (NT - t) : D_EX;
        for (int k = 0; k < steps; k += 2) {
            STEP(hA, hB, t + k,     0, 1);
            STEP(hB, hA, t + k + 1, 1, 0);
        }
        t += steps;
        if (t >= NT) break;

        // ---- boundary exchange (h1=hA, h2=hB; t is even) ----
        if (sTop) {
            #pragma unroll
            for (int i = 0; i < 5; ++i) {
                *(f4*)(sTop + i*NN) = (f4){ hA[i][0], hA[i][1], hA[i][2], hA[i][3] };
                sTop[i*NN + 4] = hA[i][4];
                *(f4*)(sTop + SLAB + i*NN) = (f4){ hB[i][0], hB[i][1], hB[i][2], hB[i][3] };
                sTop[SLAB + i*NN + 4] = hB[i][4];
            }
        }
        if (sBot) {
            #pragma unroll
            for (int i = 0; i < 5; ++i) {
                *(f4*)(sBot + i*NN) = (f4){ hA[i][0], hA[i][1], hA[i][2], hA[i][3] };
                sBot[i*NN + 4] = hA[i][4];
                *(f4*)(sBot + SLAB + i*NN) = (f4){ hB[i][0], hB[i][1], hB[i][2], hB[i][3] };
                sBot[SLAB + i*NN + 4] = hB[i][4];
            }
        }
        __threadfence();
        __syncthreads();
        if (tid == 0) {
            __hip_atomic_fetch_add(flagSelf, 1, __ATOMIC_RELEASE, __HIP_MEMORY_SCOPE_AGENT);
            if (blk > 0)
                while (__hip_atomic_load(flagUp, __ATOMIC_ACQUIRE, __HIP_MEMORY_SCOPE_AGENT) < g + 1) {}
            if (blk < NBK-1)
                while (__hip_atomic_load(flagDn, __ATOMIC_ACQUIRE, __HIP_MEMORY_SCOPE_AGENT) < g + 1) {}
        }
        __syncthreads();
        {
            const float* rp = rTop ? rTop : rBot;
            if (rp) {
                #pragma unroll
                for (int i = 0; i < 5; ++i) {
                    const f4 v1 = *(const f4*)(rp + i*NN);
                    hA[i][0] = v1[0]; hA[i][1] = v1[1]; hA[i][2] = v1[2]; hA[i][3] = v1[3];
                    hA[i][4] = rp[i*NN + 4];
                    const f4 v2 = *(const f4*)(rp + SLAB + i*NN);
                    hB[i][0] = v2[0]; hB[i][1] = v2[1]; hB[i][2] = v2[2]; hB[i][3] = v2[3];
                    hB[i][4] = rp[SLAB + i*NN + 4];
                }
                // republish refreshed edges into parity 0 (next step reads PIN=0)
                eb4[0][2*pr + 1][cg] = (f4){ hA[0][0], hA[0][1], hA[0][2], hA[0][3] };
                eb1[0][2*pr + 1][cg] = hA[0][4];
                eb4[0][2*pr + 2][cg] = (f4){ hA[4][0], hA[4][1], hA[4][2], hA[4][3] };
                eb1[0][2*pr + 2][cg] = hA[4][4];
            }
        }
        __syncthreads();
        g++;
    }
#undef STEP
}

extern "C" void kernel_launch(void* const* d_in, const int* in_sizes, int n_in,
                              void* d_out, int out_size, void* d_ws, size_t ws_size,
                              hipStream_t stream) {
    const float* x    = (const float*)d_in[0];
    const float* cmat = (const float*)d_in[1];
    const float* rho  = (const float*)d_in[2];
    const int*   si   = (const int*)d_in[3];
    const int*   sj   = (const int*)d_in[4];
    const int*   pi   = (const int*)d_in[5];
    const int*   pj   = (const int*)d_in[6];
    float*       yout = (float*)d_out;
    float*       gbuf = (float*)d_ws;
    int*         flg  = (int*)((char*)d_ws + FLAG_OFF);

    // reset exchange flags every launch (graph-capture-safe)
    hipMemsetAsync(flg, 0, NB*NBK*sizeof(int), stream);

    wave_kernel<<<NB*8, NTHR, 0, stream>>>(x, cmat, rho, si, sj, pi, pj,
                                           yout, gbuf, flg);
}

// Round 9
// 645.968 us; speedup vs baseline: 1.3655x; 1.1467x over previous
//
#include <hip/hip_runtime.h>

// WaveRNN: 2D wave equation, T=512 steps, B=4 batches of 160x160.
// Ghost-zone decomposition: 4 blocks per batch (16 active blocks), OWN=40 rows
// owned + D=20 redundant halo rows/side; exchange h1+h2 boundary slabs through
// global memory every 20 steps (25 exchanges vs 51 at D=10).
// This is the round-5 PASSED kernel verbatim with the single change D_EX 10->20
// (rounds 6-8's probe-ring/ack rework failed; reverted wholesale).
// Intra-block: 5x5 register patches, DPP column halos, split f4+f1 LDS edge
// rows, double-buffered parity -> 1 barrier/step; per-step probe stores by
// owning thread; threadfence + release-RMW + acquire-per-poll spin exchange.

#define NB   4
#define NBK  4          // blocks per batch
#define OWN  40         // owned rows per block
#define D_EX 20         // halo depth == steps between exchanges
#define NT   512
#define NN   160
#define NP   32
#define C_DT 0.16f

#define TGX   32
#define TPR   16                 // max patch-rows (interior: (40+2*20)/5)
#define NTHR  (TPR*TGX)          // 512
#define EROWS (2*TPR + 2)        // 34; slots 0 and 33 are zero guards
#define K_ENT 6

#define SLAB      (D_EX*NN)              // floats per (side,level) slab: 3200
#define GB_FLOATS (NB*NBK*2*2*SLAB)      // 204800 floats = 819200 B
#define FLAG_OFF  (GB_FLOATS*4)          // byte offset of flags in d_ws

typedef float f4 __attribute__((ext_vector_type(4)));

#if defined(__has_builtin)
#if __has_builtin(__builtin_amdgcn_update_dpp)
#define HAVE_DPP 1
#endif
#endif

__device__ __forceinline__ float shr1(float v) {   // lane i <- lane i-1
#ifdef HAVE_DPP
    return __int_as_float(__builtin_amdgcn_update_dpp(
        0, __float_as_int(v), 0x138 /*wave_shr:1*/, 0xf, 0xf, true));
#else
    return __shfl_up(v, 1, 64);
#endif
}
__device__ __forceinline__ float shl1(float v) {   // lane i <- lane i+1
#ifdef HAVE_DPP
    return __int_as_float(__builtin_amdgcn_update_dpp(
        0, __float_as_int(v), 0x130 /*wave_shl:1*/, 0xf, 0xf, true));
#else
    return __shfl_down(v, 1, 64);
#endif
}

__global__ __launch_bounds__(NTHR, 1) void wave_kernel(
    const float* __restrict__ x,      // [B][T]
    const float* __restrict__ cmat,   // [N][N]
    const float* __restrict__ rho,    // [N][N]
    const int*   __restrict__ src_i_p,
    const int*   __restrict__ src_j_p,
    const int*   __restrict__ probe_i,// [P]
    const int*   __restrict__ probe_j,// [P]
    float*       __restrict__ y,      // [B][T][P]
    float*       __restrict__ gw,     // exchange slabs [B][NBK][side][lvl][20][160]
    int*         __restrict__ flags)  // [B*NBK], zeroed per launch
{
    __shared__ f4    eb4[2][EROWS][TGX];
    __shared__ float eb1[2][EROWS][TGX];
    __shared__ float xbuf[NT];
    __shared__ int   pco[2*NP];

    const int bid   = blockIdx.x;
    const int batch = bid & 7;        // same-batch blocks likely share an XCD
    if (batch >= NB) return;          // idle pad blocks exit immediately
    const int blk   = bid >> 3;

    const int own_s = blk * OWN;
    const int own_e = own_s + OWN;
    const int ext_s = (own_s - D_EX < 0)  ? 0  : own_s - D_EX;
    const int ext_e = (own_e + D_EX > NN) ? NN : own_e + D_EX;
    const int npr   = (ext_e - ext_s) / 5;

    const int tid = threadIdx.x;
    const int pr  = tid >> 5;
    const int cg  = tid & 31;
    const bool act = pr < npr;
    const int gr0 = ext_s + 5*pr;     // global row of patch top (valid if act)
    const int c0  = 5*cg;

    // ---- init LDS ----
    {
        float* e4 = (float*)&eb4[0][0][0];
        for (int i = tid; i < 2*EROWS*TGX*4; i += NTHR) e4[i] = 0.0f;
        float* e1 = &eb1[0][0][0];
        for (int i = tid; i < 2*EROWS*TGX; i += NTHR) e1[i] = 0.0f;
        for (int i = tid; i < NT; i += NTHR) xbuf[i] = x[batch*NT + i];
        if (tid < NP) { pco[tid] = probe_i[tid]; pco[NP + tid] = probe_j[tid]; }
    }

    const int si = src_i_p[0];
    const int sj = src_j_p[0];

    float hA[5][5], hB[5][5], cf[5][5], c2[5][5];
    #pragma unroll
    for (int i = 0; i < 5; ++i)
        #pragma unroll
        for (int j = 0; j < 5; ++j) {
            float cfv = 0.0f;
            if (act) {
                const float cc = cmat[(gr0+i)*NN + (c0+j)];
                const float rr = rho[(gr0+i)*NN + (c0+j)];
                cfv = C_DT * cc * cc / rr;
            }
            cf[i][j] = cfv;
            c2[i][j] = 2.0f - 4.0f * cfv;
            hA[i][j] = 0.0f;
            hB[i][j] = 0.0f;
        }

    unsigned srcMask = 0;
    if (act && gr0 <= si && si < gr0 + 5 && c0 <= sj && sj < c0 + 5)
        srcMask = 1u << ((si - gr0)*5 + (sj - c0));

    __syncthreads();

    // per-thread probe entries over OWNED cells only (exact every step)
    unsigned long long ent = 0;
    int ecnt = 0;
    if (act && gr0 >= own_s && gr0 < own_e) {
        for (int p = 0; p < NP; ++p) {
            const int r = pco[p], c = pco[NP + p];
            if (r >= gr0 && r < gr0 + 5 && c >= c0 && c < c0 + 5) {
                const int ij = (r - gr0)*5 + (c - c0);
                if (ecnt < K_ENT)
                    ent |= ((unsigned long long)(unsigned)(p | (ij << 5))) << (10*ecnt);
                ecnt++;
            }
        }
    }

    // ---- exchange pointers (per-thread constant) ----
    const int bid2 = batch*NBK + blk;
    float* sTop = nullptr; float* sBot = nullptr;
    const float* rTop = nullptr; const float* rBot = nullptr;
    if (blk > 0 && gr0 >= own_s && gr0 < own_s + D_EX)
        sTop = gw + (size_t)(bid2*2 + 0)*2*SLAB + (gr0 - own_s)*NN + c0;
    if (blk < NBK-1 && gr0 >= own_e - D_EX && gr0 < own_e)
        sBot = gw + (size_t)(bid2*2 + 1)*2*SLAB + (gr0 - (own_e - D_EX))*NN + c0;
    if (blk > 0 && act && gr0 < own_s)
        rTop = gw + (size_t)((bid2-1)*2 + 1)*2*SLAB + (gr0 - (own_s - D_EX))*NN + c0;
    if (blk < NBK-1 && act && gr0 >= own_e)
        rBot = gw + (size_t)((bid2+1)*2 + 0)*2*SLAB + (gr0 - own_e)*NN + c0;
    int* const flagSelf = &flags[bid2];
    int* const flagUp   = &flags[bid2 - 1];
    int* const flagDn   = &flags[bid2 + 1];

    float* const yb = y + (size_t)batch*NT*NP;

#define STEP(HS, HD, TT, PIN, POUT)                                           \
    {                                                                         \
        const int tt = (TT);                                                  \
        const f4    nh4 = eb4[PIN][2*pr    ][cg];                             \
        const float nhe = eb1[PIN][2*pr    ][cg];                             \
        const f4    sh4 = eb4[PIN][2*pr + 3][cg];                             \
        const float she = eb1[PIN][2*pr + 3][cg];                             \
        const float nh[5] = { nh4[0], nh4[1], nh4[2], nh4[3], nhe };          \
        const float sh[5] = { sh4[0], sh4[1], sh4[2], sh4[3], she };          \
        float wh[5], eh[5];                                                   \
        _Pragma("unroll")                                                     \
        for (int i = 0; i < 5; ++i) {                                         \
            const float tw = shr1(HS[i][4]);                                  \
            wh[i] = (cg == 0) ? 0.0f : tw;                                    \
            const float te = shl1(HS[i][0]);                                  \
            eh[i] = (cg == TGX-1) ? 0.0f : te;                                \
        }                                                                     \
        _Pragma("unroll")                                                     \
        for (int i = 0; i < 5; ++i) {                                         \
            _Pragma("unroll")                                                 \
            for (int j = 0; j < 5; ++j) {                                     \
                const float up = (i == 0) ? nh[j] : HS[i-1][j];               \
                const float dn = (i == 4) ? sh[j] : HS[i+1][j];               \
                const float lf = (j == 0) ? wh[i] : HS[i][j-1];               \
                const float rt = (j == 4) ? eh[i] : HS[i][j+1];               \
                const float s  = (up + dn) + (lf + rt);                       \
                const float t1 = __builtin_fmaf(c2[i][j], HS[i][j], -HD[i][j]); \
                HD[i][j] = __builtin_fmaf(cf[i][j], s, t1);                   \
            }                                                                 \
        }                                                                     \
        if (srcMask) {                                                        \
            const float xt = xbuf[tt];                                        \
            _Pragma("unroll")                                                 \
            for (int i = 0; i < 5; ++i)                                       \
                _Pragma("unroll")                                             \
                for (int j = 0; j < 5; ++j)                                   \
                    if (srcMask & (1u << (i*5 + j))) HD[i][j] += xt;          \
        }                                                                     \
        eb4[POUT][2*pr + 1][cg] = (f4){ HD[0][0], HD[0][1], HD[0][2], HD[0][3] }; \
        eb1[POUT][2*pr + 1][cg] = HD[0][4];                                   \
        eb4[POUT][2*pr + 2][cg] = (f4){ HD[4][0], HD[4][1], HD[4][2], HD[4][3] }; \
        eb1[POUT][2*pr + 2][cg] = HD[4][4];                                   \
        if (ecnt) {                                                           \
            float* const yt = yb + (size_t)tt * NP;                           \
            _Pragma("unroll")                                                 \
            for (int k = 0; k < K_ENT; ++k) {                                 \
                if (k < ecnt) {                                               \
                    const int e  = (int)((ent >> (10*k)) & 0x3FF);            \
                    const int p  = e & 31;                                    \
                    const int ij = e >> 5;                                    \
                    float v = 0.0f;                                           \
                    _Pragma("unroll")                                         \
                    for (int i = 0; i < 5; ++i)                               \
                        _Pragma("unroll")                                     \
                        for (int j = 0; j < 5; ++j)                           \
                            if (ij == i*5 + j) v = HD[i][j];                  \
                    yt[p] = v;                                                \
                }                                                             \
            }                                                                 \
        }                                                                     \
        __syncthreads();                                                      \
    }

    int t = 0, g = 0;
    while (t < NT) {
        const int steps = (NT - t < D_EX) ? (NT - t) : D_EX;
        for (int k = 0; k < steps; k += 2) {
            STEP(hA, hB, t + k,     0, 1);
            STEP(hB, hA, t + k + 1, 1, 0);
        }
        t += steps;
        if (t >= NT) break;

        // ---- boundary exchange (h1=hA, h2=hB; t is even) ----
        if (sTop) {
            #pragma unroll
            for (int i = 0; i < 5; ++i) {
                *(f4*)(sTop + i*NN) = (f4){ hA[i][0], hA[i][1], hA[i][2], hA[i][3] };
                sTop[i*NN + 4] = hA[i][4];
                *(f4*)(sTop + SLAB + i*NN) = (f4){ hB[i][0], hB[i][1], hB[i][2], hB[i][3] };
                sTop[SLAB + i*NN + 4] = hB[i][4];
            }
        }
        if (sBot) {
            #pragma unroll
            for (int i = 0; i < 5; ++i) {
                *(f4*)(sBot + i*NN) = (f4){ hA[i][0], hA[i][1], hA[i][2], hA[i][3] };
                sBot[i*NN + 4] = hA[i][4];
                *(f4*)(sBot + SLAB + i*NN) = (f4){ hB[i][0], hB[i][1], hB[i][2], hB[i][3] };
                sBot[SLAB + i*NN + 4] = hB[i][4];
            }
        }
        __threadfence();
        __syncthreads();
        if (tid == 0) {
            __hip_atomic_fetch_add(flagSelf, 1, __ATOMIC_RELEASE, __HIP_MEMORY_SCOPE_AGENT);
            if (blk > 0)
                while (__hip_atomic_load(flagUp, __ATOMIC_ACQUIRE, __HIP_MEMORY_SCOPE_AGENT) < g + 1) {}
            if (blk < NBK-1)
                while (__hip_atomic_load(flagDn, __ATOMIC_ACQUIRE, __HIP_MEMORY_SCOPE_AGENT) < g + 1) {}
        }
        __syncthreads();
        {
            const float* rp = rTop ? rTop : rBot;
            if (rp) {
                #pragma unroll
                for (int i = 0; i < 5; ++i) {
                    const f4 v1 = *(const f4*)(rp + i*NN);
                    hA[i][0] = v1[0]; hA[i][1] = v1[1]; hA[i][2] = v1[2]; hA[i][3] = v1[3];
                    hA[i][4] = rp[i*NN + 4];
                    const f4 v2 = *(const f4*)(rp + SLAB + i*NN);
                    hB[i][0] = v2[0]; hB[i][1] = v2[1]; hB[i][2] = v2[2]; hB[i][3] = v2[3];
                    hB[i][4] = rp[SLAB + i*NN + 4];
                }
                // republish refreshed edges into parity 0 (next step reads PIN=0)
                eb4[0][2*pr + 1][cg] = (f4){ hA[0][0], hA[0][1], hA[0][2], hA[0][3] };
                eb1[0][2*pr + 1][cg] = hA[0][4];
                eb4[0][2*pr + 2][cg] = (f4){ hA[4][0], hA[4][1], hA[4][2], hA[4][3] };
                eb1[0][2*pr + 2][cg] = hA[4][4];
            }
        }
        __syncthreads();
        g++;
    }
#undef STEP
}

extern "C" void kernel_launch(void* const* d_in, const int* in_sizes, int n_in,
                              void* d_out, int out_size, void* d_ws, size_t ws_size,
                              hipStream_t stream) {
    const float* x    = (const float*)d_in[0];
    const float* cmat = (const float*)d_in[1];
    const float* rho  = (const float*)d_in[2];
    const int*   si   = (const int*)d_in[3];
    const int*   sj   = (const int*)d_in[4];
    const int*   pi   = (const int*)d_in[5];
    const int*   pj   = (const int*)d_in[6];
    float*       yout = (float*)d_out;
    float*       gbuf = (float*)d_ws;
    int*         flg  = (int*)((char*)d_ws + FLAG_OFF);

    // reset exchange flags every launch (graph-capture-safe)
    hipMemsetAsync(flg, 0, NB*NBK*sizeof(int), stream);

    wave_kernel<<<NB*8, NTHR, 0, stream>>>(x, cmat, rho, si, sj, pi, pj,
                                           yout, gbuf, flg);
}